// Round 7
// baseline (439.026 us; speedup 1.0000x reference)
//
#include <hip/hip_runtime.h>
#include <float.h>

#define NB 32
#define NBCE 32
#define L 128
#define NT 1024
#define R 132                      /* row stride (dwords) */
#define PAD 40                     /* masked tail overreads stay in LDS */
#define LOGMIN -87.49823f          /* ln(1e-38) */

// ---- mask dtype runtime detection (element [0] is guaranteed true: lens >= 64) ----
__device__ __forceinline__ int mask_mode(const void* p) {
    unsigned int v = ((const unsigned int*)p)[0];
    if (v == 1u) return 1;
    if (v == 0x3F800000u) return 2;
    return 0;
}
__device__ __forceinline__ bool mask_at(const void* p, int mode, int idx) {
    if (mode == 1) return ((const int*)p)[idx] != 0;
    if (mode == 2) return ((const float*)p)[idx] != 0.0f;
    return ((const unsigned char*)p)[idx] != 0;
}

__device__ __forceinline__ float lse2(float a, float b) {
    return fmaxf(a, b) + log1pf(__expf(-fabsf(a - b)));
}

// ---- DPP butterfly reduce within aligned subgroups of 8 or 16 lanes ----
template<int C>
__device__ __forceinline__ float dppf(float x) {
    return __int_as_float(__builtin_amdgcn_mov_dpp(__float_as_int(x), C, 0xF, 0xF, true));
}
template<int T>
__device__ __forceinline__ float bfly_max(float x) {
    x = fmaxf(x, dppf<0xB1>(x));
    x = fmaxf(x, dppf<0x4E>(x));
    x = fmaxf(x, dppf<0x141>(x));
    if (T == 16) x = fmaxf(x, dppf<0x140>(x));
    return x;
}
template<int T>
__device__ __forceinline__ float bfly_add(float x) {
    x += dppf<0xB1>(x);
    x += dppf<0x4E>(x);
    x += dppf<0x141>(x);
    if (T == 16) x += dppf<0x140>(x);
    return x;
}

// ---- term loader: term t = sub + m*T from two contiguous streams ----
template<int T, int NU>
__device__ __forceinline__ void load_terms(float* v, int sub, int nterm,
                                           const float* p1, const float* p2, float& mloc) {
    p1 += sub; p2 += sub;
#pragma unroll
    for (int m = 0; m < NU; ++m) {
        if (m * T >= nterm) break;
        float a = p1[m * T] + p2[m * T];
        a = (sub + m * T < nterm) ? a : -FLT_MAX;
        v[m] = a;
        mloc = fmaxf(mloc, a);
    }
}
template<int T, int NU>
__device__ __forceinline__ void sum_exp(const float* v, int nterm, float M, float& s) {
#pragma unroll
    for (int m = 0; m < NU; ++m) {
        if (m * T >= nterm) break;
        s += __expf(v[m] - M);
    }
}

// one-stream LSE partial: all lanes get (M, S); empty -> (-FLT_MAX, 0)
template<int T, int NU>
__device__ __forceinline__ void lse_part1(const float* p1, const float* p2, int nt,
                                          int sub, float& M, float& S) {
    float v[NU]; float mloc = -FLT_MAX;
    load_terms<T, NU>(v, sub, nt, p1, p2, mloc);
    float Mv = bfly_max<T>(mloc);
    float s = 0.0f;
    sum_exp<T, NU>(v, nt, Mv, s);
    S = bfly_add<T>(s);
    M = Mv;
}
// two-stream LSE partial (shared max)
template<int T, int NU1, int NU2>
__device__ __forceinline__ void lse_part2(const float* a1, const float* a2, int nt1,
                                          const float* b1, const float* b2, int nt2,
                                          int sub, float& M, float& S) {
    float v1[NU1]; float v2[NU2]; float mloc = -FLT_MAX;
    load_terms<T, NU1>(v1, sub, nt1, a1, a2, mloc);
    load_terms<T, NU2>(v2, sub, nt2, b1, b2, mloc);
    float Mv = bfly_max<T>(mloc);
    float s = 0.0f;
    sum_exp<T, NU1>(v1, nt1, Mv, s);
    sum_exp<T, NU2>(v2, nt2, Mv, s);
    S = bfly_add<T>(s);
    M = Mv;
}

// ---- online merges ----
__device__ __forceinline__ void omerge(float t, float& m, float& s) {
    float nm = fmaxf(m, t);
    s = s * __expf(m - nm) + __expf(t - nm);
    m = nm;
}
__device__ __forceinline__ void omerge_mask(float t, bool mk, float& m, float& s) {
    float tm = mk ? t : -FLT_MAX;
    float nm = fmaxf(m, tm);
    s = s * __expf(m - nm) + (mk ? __expf(t - nm) : 0.0f);
    m = nm;
}

// ---- cross-wave neighbor exchange: per-cell monotone epoch flags in LDS ----
__device__ __forceinline__ void pub(int* f, int ep) {
    __hip_atomic_store(f, ep, __ATOMIC_RELEASE, __HIP_MEMORY_SCOPE_WORKGROUP);
}
__device__ __forceinline__ void waitflag(int* f, int ep) {
    while (__hip_atomic_load(f, __ATOMIC_ACQUIRE, __HIP_MEMORY_SCOPE_WORKGROUP) < ep) {}
}

// ======== paired inside interval: widths (w, w+1), one barrier ========
// phase 1 (width w): exactly the proven R0 cell. phase 2 (width w+1): bulk = w-1 old
// terms; end terms use own val1 (reg) and neighbor cell's val1 (shfl / flag+LDS).
template<int T>
__device__ __forceinline__ void inside_pair(float* Am, int* flag, int n, int w, int tid) {
    const int i = tid / T, sub = tid % T;
    const int c = n - w;
    const int j = i + w, j2 = j + 1;
    const bool act1 = (i < c);
    const bool act2 = (w + 1 < n) && (i < c - 1);
    float val1 = -FLT_MAX;
    if (act1) {
        float M, S;
        lse_part1<T, 8>(&Am[i * R + i], &Am[j * R + i + 1], w, sub, M, S);
        val1 = Am[i * R + j] + M + __logf(S);      // slot holds sc
        if (sub == 0) {
            Am[i * R + j] = val1;
            Am[j * R + i] = val1;
            pub(&flag[i], w);
        }
    }
    float M2 = -FLT_MAX, S2 = 0.0f;
    if (act2)   // bulk of width w+1: k in [i+1, i+w-1], both sides width <= w-1 (old)
        lse_part1<T, 8>(&Am[i * R + i + 1], &Am[j2 * R + i + 2], w - 1, sub, M2, S2);
    float sh = __shfl_down(val1, T);               // neighbor subgroup's val1
    if (act2) {
        float nb;
        if ((i & (64 / T - 1)) == (64 / T - 1)) {  // last subgroup in wave: cross-wave
            waitflag(&flag[i + 1], w);
            nb = Am[(i + 1) * R + j2];             // alpha[i+1, i+1+w]
        } else nb = sh;
        float m = M2, s = S2;
        omerge(val1 + Am[j2 * R + j2], m, s);      // k=i+w: own + diag(j2)
        omerge(Am[i * R + i] + nb, m, s);          // k=i:   diag(i) + neighbor
        float val2 = Am[i * R + j2] + m + __logf(s);
        if (sub == 0) { Am[i * R + j2] = val2; Am[j2 * R + i] = val2; }
    }
}

// ======== paired outside interval: widths (w, w-1), one barrier ========
template<int T, int NU>
__device__ __forceinline__ void outside_pair(const float* Am, float* Gm, int* flag,
                                             int n, int w, int ep, int tid) {
    const int i = tid / T, sub = tid % T;
    const int c = n - w;
    const int j = i + w, jp = j - 1;
    const bool act1 = (i < c);
    const bool act2 = (w >= 2) && (i <= c);
    float val1 = -FLT_MAX;
    if (act1) {
        float M, S;
        const float* av = &Am[(i >= 1 ? i - 1 : 0) * R];
        lse_part2<T, NU, NU>(&Gm[i * R + j + 1], &Am[(j + 1) * R + j + 1], n - 1 - j,
                             &Gm[j * R], av, i, sub, M, S);
        val1 = Gm[i * R + j] + M + __logf(S);      // slot holds sc
        if (sub == 0) {
            Gm[i * R + j] = val1;
            Gm[j * R + i] = val1;
            pub(&flag[i], ep);
        }
    }
    float M2 = -FLT_MAX, S2 = 0.0f;
    if (act2) {  // bulk of width w-1: U k in [j+1, n) (widths >= w+1), V k in [0, i-2]
        const float* av = &Am[(i >= 1 ? i - 1 : 0) * R];
        const int jcl = min(j, n - 1);
        lse_part2<T, NU, NU>(&Gm[i * R + j + 1], &Am[jcl * R + j + 1], n - j - 1,
                             &Gm[jp * R], av, i - 1, sub, M2, S2);
    }
    float sh = __shfl_up(val1, T);                 // neighbor (i-1) subgroup's val1
    if (act2) {
        float nb = sh;
        if ((i & (64 / T - 1)) == 0) {             // first subgroup in wave: cross-wave
            if (i >= 1) {
                waitflag(&flag[i - 1], ep);
                nb = Gm[(i - 1) * R + jp];         // gamma[i-1, i-1+w]
            }
        }
        float m = M2, s = S2;
        const int jd = min(j, n - 1);
        omerge_mask(val1 + Am[jd * R + jd], i + w < n, m, s);  // k=j'+1: own gamma + diag
        const int id = (i >= 1) ? i - 1 : 0;
        omerge_mask(nb + Am[id * R + id], i >= 1, m, s);       // k=i-1: neighbor + diag
        float val2 = Gm[i * R + jp] + m + __logf(s);
        if (sub == 0) { Gm[i * R + jp] = val2; Gm[jp * R + i] = val2; }
    }
}

// ================= fused kernel: blocks [0,NB) = per-batch DP; [NB,NB+NBCE) = BCE =================
__global__ __launch_bounds__(NT, 1) void tree_dp_kernel(
    const float* __restrict__ logits,
    const int*   __restrict__ spans_ind,
    const void*  __restrict__ maskspan,
    const float* __restrict__ ph, const float* __restrict__ pt,
    const int* __restrict__ ph_ind, const int* __restrict__ pt_ind,
    const void* __restrict__ maskarc,
    double*      __restrict__ ws)
{
    const int tid = threadIdx.x;

    // ---------------- BCE blocks ----------------
    if (blockIdx.x >= NB) {
        const int mode = mask_mode(maskarc);
        const int tot = NB * L * L;
        double sph = 0.0, spt = 0.0, cnt = 0.0;
        for (int idx = (blockIdx.x - NB) * NT + tid; idx < tot; idx += NBCE * NT) {
            if (mask_at(maskarc, mode, idx)) {
                float x = ph[idx]; float y = (float)ph_ind[idx];
                sph += (double)(fmaxf(x, 0.0f) - x * y + log1pf(__expf(-fabsf(x))));
                x = pt[idx]; y = (float)pt_ind[idx];
                spt += (double)(fmaxf(x, 0.0f) - x * y + log1pf(__expf(-fabsf(x))));
                cnt += 1.0;
            }
        }
        for (int off = 32; off > 0; off >>= 1) {
            sph += __shfl_down(sph, off);
            spt += __shfl_down(spt, off);
            cnt += __shfl_down(cnt, off);
        }
        if ((tid & 63) == 0) {
            atomicAdd(&ws[2], sph); atomicAdd(&ws[3], spt); atomicAdd(&ws[4], cnt);
        }
        return;
    }

    // ---------------- DP blocks ----------------
    // Am / Gm: mirror squares, Am[i*R+j] == Am[j*R+i] == alpha[i,j]; same for gamma.
    // Untouched slots hold sc.
    __shared__ __align__(16) float Am[L * R + PAD];
    __shared__ __align__(16) float Gm[L * R + PAD];
    __shared__ int flag[128];

    const int b = blockIdx.x;
    const int mbase = b * L * L;
    const int mode = mask_mode(maskspan);

    int predv = (tid < L) && mask_at(maskspan, mode, mbase + tid);
    const int n = __syncthreads_count(predv);

    const float* lg = logits + (size_t)b * L * L * 2;
    const int* si = spans_ind + mbase;

    if (tid < 128) flag[tid] = 0;
    // ---- init: sc into both mirror halves of Am and Gm ----
    for (int e = tid; e < L * L; e += NT) {
        int ii = e >> 7, jj = e & (L - 1);
        if (ii <= jj && jj < n) {
            const float* p = lg + (size_t)e * 2;
            float v = lse2(p[0], p[1]);
            Am[ii * R + jj] = v; Am[jj * R + ii] = v;
            Gm[ii * R + jj] = v; Gm[jj * R + ii] = v;
        }
    }
    __syncthreads();

    // ======== INSIDE: width pairs (w, w+1) ========
    for (int w = 1; w < n; w += 2) {
        if (n - w > 64) inside_pair<8>(Am, flag, n, w, tid);
        else            inside_pair<16>(Am, flag, n, w, tid);
        __syncthreads();
    }

    const float logZ = Am[n - 1];   // alpha[0, n-1]

    // ======== OUTSIDE: width pairs (w, w-1), w = n-2, n-4, ... ========
    for (int w = n - 2; w >= 1; w -= 2) {
        const int ep = 2 * n - w;   // monotone, continues past inside epochs
        if (n - w + 1 > 64) outside_pair<8, 16>(Am, Gm, flag, n, w, ep, tid);
        else                outside_pair<16, 4>(Am, Gm, flag, n, w, ep, tid);
        __syncthreads();
    }

    // ---- fused w=0 outside (beta_ii) + diagonal loss ----
    double local = 0.0;
    {
        const int i = tid >> 3, sub = tid & 7;
        if (i < n) {
            float M, S;
            const float* pa1 = &Am[(i + 1 < n ? i + 1 : 0) * R];
            const float* pa2 = &Am[(i >= 1 ? i - 1 : 0) * R];
            lse_part2<8, 16, 16>(&Gm[i * R + i + 1], pa1 + i + 1, n - 1 - i,
                                 &Gm[i * R], pa2, i, sub, M, S);
            if (sub == 0) {
                float beta_ii = M + __logf(S);
                const float* p = lg + ((size_t)i * L + i) * 2;
                float lc = (si[i * L + i] == 2) ? p[1] : p[0];
                local += (double)fmaxf(beta_ii - logZ + lc, LOGMIN);
            }
        }
    }

    // ---- strict-upper loss ----
    for (int e = tid; e < L * L; e += NT) {
        int ii = e >> 7, jj = e & (L - 1);
        if (ii < jj && jj < n) {
            const float* p = lg + (size_t)e * 2;
            float a = p[0], cc = p[1];
            float sc = lse2(a, cc);
            float lc = (si[e] == 2) ? cc : a;
            float logm = Am[ii * R + jj] + Gm[ii * R + jj] - logZ + lc - 2.0f * sc;
            local += (double)fmaxf(logm, LOGMIN);
        }
    }

    for (int off = 32; off > 0; off >>= 1)
        local += __shfl_down(local, off);
    if ((tid & 63) == 0) atomicAdd(&ws[0], local);
    if (tid == 0) atomicAdd(&ws[1], (double)n);
}

// ================= finalize =================
__global__ void finalize_kernel(const double* __restrict__ ws, float* __restrict__ out) {
    double loss_spans = -ws[0] / ws[1];
    double bce = (ws[2] + ws[3]) / ws[4];
    out[0] = (float)(0.5 * loss_spans + 0.5 * bce);
}

extern "C" void kernel_launch(void* const* d_in, const int* in_sizes, int n_in,
                              void* d_out, int out_size, void* d_ws, size_t ws_size,
                              hipStream_t stream) {
    (void)in_sizes; (void)n_in; (void)out_size; (void)ws_size;
    const float* span_logits = (const float*)d_in[0];
    const float* ph          = (const float*)d_in[1];
    const float* pt          = (const float*)d_in[2];
    /* d_in[3] = ph_arc: unused by reference */
    const int*   spans_ind   = (const int*)d_in[4];
    const int*   ph_ind      = (const int*)d_in[5];
    const int*   pt_ind      = (const int*)d_in[6];
    const void*  maskspan    = d_in[7];
    const void*  maskarc     = d_in[8];
    double* ws = (double*)d_ws;
    float* out = (float*)d_out;

    hipMemsetAsync(d_ws, 0, 5 * sizeof(double), stream);
    hipLaunchKernelGGL(tree_dp_kernel, dim3(NB + NBCE), dim3(NT), 0, stream,
                       span_logits, spans_ind, maskspan,
                       ph, pt, ph_ind, pt_ind, maskarc, ws);
    hipLaunchKernelGGL(finalize_kernel, dim3(1), dim3(1), 0, stream, ws, out);
}